// Round 3
// baseline (306.381 us; speedup 1.0000x reference)
//
#include <hip/hip_runtime.h>
#include <math.h>

// Gaussian NLL + analytic grad + Hessian wrt (mu, pre-softplus-std).
// Streaming: 12 B/elem in, 28 B/elem out -> 335.5 MB @ N=2^23, floor ~53 us.
//
// R2 insight (rocprof): timed dur includes a ~142 us harness poison fill
// (939 MB @ 6.6 TB/s). Kernel portion ~140 us => 2.7 TB/s effective, 2.5x
// off the same-run fill ceiling. Lever: bigger per-lane transactions.
//
// This revision: 2 elements per thread ("pair" processing):
//   loads : y_pred v4f (16 B/lane), y_true v2f (8 B/lane)
//   stores: loss v2f (8B), g v4f (16B), h 2x v4f (32B)
// Halves VMEM instruction count per byte; two independent element
// pipelines per thread double ILP. Grid 2048 x 256, grid-stride (8 pair
// iters/thread). Nontemporal retained (write-once / read-once streams).

typedef float v2f __attribute__((ext_vector_type(2)));
typedef float v4f __attribute__((ext_vector_type(4)));

__device__ __forceinline__ void nll_elem(float mu, float s, float y,
                                         float& L, float& g0, float& g1,
                                         float& h00, float& h01, float& h11)
{
    // stable softplus: max(s,0) + log1p(exp(-|s|))
    float e    = __expf(-fabsf(s));
    float rec  = 1.0f / (1.0f + e);           // sigmoid(|s|)
    float sig  = (s >= 0.0f) ? rec : e * rec; // sigmoid(s), reuses e
    float stdv = fmaxf(s, 0.0f) + __logf(1.0f + e);
    float inv  = 1.0f / stdv;
    float z    = (y - mu) * inv;
    float z2   = z * z;

    L  = 0.5f * z2 + __logf(stdv) + 0.91893853320467274178f; // +0.5*log(2*pi)
    g0 = -z * inv;
    g1 = sig * (1.0f - z2) * inv;

    float inv2 = inv * inv;
    h00 = inv2;
    h01 = 2.0f * z * sig * inv2;
    h11 = sig * (1.0f - sig) * (1.0f - z2) * inv
        + sig * sig * (3.0f * z2 - 1.0f) * inv2;
}

__global__ __launch_bounds__(256) void unll_kernel(
    const v4f* __restrict__ yp2,   // [N/2] of (mu0,s0,mu1,s1)
    const v2f* __restrict__ yt2,   // [N/2] of (y0,y1)
    v2f* __restrict__ loss2,       // [N/2]
    v4f* __restrict__ g2,          // [N/2] of (g00,g01,g10,g11)
    v4f* __restrict__ h1,          // [N]   of (h00,h01,h10,h11)
    int npairs)
{
    const int stride = gridDim.x * blockDim.x;
    for (int ip = blockIdx.x * blockDim.x + threadIdx.x; ip < npairs; ip += stride) {
        v4f p = __builtin_nontemporal_load(&yp2[ip]);
        v2f y = __builtin_nontemporal_load(&yt2[ip]);

        float L0, g00, g01, h000, h001, h011;
        float L1, g10, g11, h100, h101, h111;
        nll_elem(p.x, p.y, y.x, L0, g00, g01, h000, h001, h011);
        nll_elem(p.z, p.w, y.y, L1, g10, g11, h100, h101, h111);

        v2f Lv; Lv.x = L0; Lv.y = L1;
        v4f gv; gv.x = g00; gv.y = g01; gv.z = g10; gv.w = g11;
        v4f h0v; h0v.x = h000; h0v.y = h001; h0v.z = h001; h0v.w = h011;
        v4f h1v; h1v.x = h100; h1v.y = h101; h1v.z = h101; h1v.w = h111;

        __builtin_nontemporal_store(Lv,  &loss2[ip]);
        __builtin_nontemporal_store(gv,  &g2[ip]);
        __builtin_nontemporal_store(h0v, &h1[2 * ip]);
        __builtin_nontemporal_store(h1v, &h1[2 * ip + 1]);
    }
}

// Scalar tail for odd N (not hit at N=2^23, kept for correctness).
__global__ void unll_tail(const float* __restrict__ yp, const float* __restrict__ yt,
                          float* __restrict__ out_loss, float* __restrict__ out_g,
                          float* __restrict__ out_h, int i)
{
    float L, g0, g1, h00, h01, h11;
    nll_elem(yp[2 * i], yp[2 * i + 1], yt[i], L, g0, g1, h00, h01, h11);
    out_loss[i] = L;
    out_g[2 * i] = g0; out_g[2 * i + 1] = g1;
    out_h[4 * i] = h00; out_h[4 * i + 1] = h01;
    out_h[4 * i + 2] = h01; out_h[4 * i + 3] = h11;
}

extern "C" void kernel_launch(void* const* d_in, const int* in_sizes, int n_in,
                              void* d_out, int out_size, void* d_ws, size_t ws_size,
                              hipStream_t stream) {
    const float* y_pred = (const float*)d_in[0];  // [N,2]
    const float* y_true = (const float*)d_in[1];  // [N]
    float* out = (float*)d_out;                   // loss[N] | d[2N] | dd[4N]

    const int N = in_sizes[1];
    const int NP = N / 2;

    float* out_loss = out;
    float* out_g    = out + (size_t)N;
    float* out_h    = out + (size_t)3 * N;

    const int block = 256;
    int grid = (NP + block - 1) / block;
    if (grid > 2048) grid = 2048;   // 256 CUs x 8 blocks; grid-stride inside
    unll_kernel<<<grid, block, 0, stream>>>(
        (const v4f*)y_pred, (const v2f*)y_true,
        (v2f*)out_loss, (v4f*)out_g, (v4f*)out_h, NP);

    if (N & 1) {
        unll_tail<<<1, 1, 0, stream>>>(y_pred, y_true, out_loss, out_g, out_h, N - 1);
    }
}